// Round 4
// baseline (228.579 us; speedup 1.0000x reference)
//
#include <hip/hip_runtime.h>
#include <stdint.h>

#define N 8192
#define D 256          // elements per row == bytes per fp8 row == full K
#define INV_T 20.0f
#define BM 128
#define BN 128

typedef __attribute__((ext_vector_type(16))) float f32x16;
typedef __attribute__((ext_vector_type(2))) long i64x2;

typedef __attribute__((address_space(3))) uint32_t lds_u32;
typedef __attribute__((address_space(1))) const uint32_t gbl_u32;

// Kernel 1: per-row fp32 normalize -> fp8 e4m3 (OCP) copies; c[i]=(e_i.p_i)/T exact fp32.
// Also zeroes out[0] (poisoned 0xAA; reduce kernel atomicAdds into it).
__global__ __launch_bounds__(256) void normalize_kernel(
    const float* __restrict__ e, const float* __restrict__ p, const float* __restrict__ n,
    uint32_t* __restrict__ eb, uint32_t* __restrict__ pb, uint32_t* __restrict__ nb,
    float* __restrict__ cbuf, float* __restrict__ out0) {
  const int tid = threadIdx.x;
  const int wave = tid >> 6, lane = tid & 63;
  const int row = blockIdx.x * 4 + wave;          // one wave per row
  if (blockIdx.x == 0 && tid == 0) out0[0] = 0.0f;

  const float4 ev = ((const float4*)(e + (size_t)row * D))[lane];
  const float4 pv = ((const float4*)(p + (size_t)row * D))[lane];
  const float4 nv = ((const float4*)(n + (size_t)row * D))[lane];

  float sse = ev.x*ev.x + ev.y*ev.y + ev.z*ev.z + ev.w*ev.w;
  float ssp = pv.x*pv.x + pv.y*pv.y + pv.z*pv.z + pv.w*pv.w;
  float ssn = nv.x*nv.x + nv.y*nv.y + nv.z*nv.z + nv.w*nv.w;
  float dep = ev.x*pv.x + ev.y*pv.y + ev.z*pv.z + ev.w*pv.w;
#pragma unroll
  for (int m = 1; m < 64; m <<= 1) {
    sse += __shfl_xor(sse, m);
    ssp += __shfl_xor(ssp, m);
    ssn += __shfl_xor(ssn, m);
    dep += __shfl_xor(dep, m);
  }
  const float se = 1.0f / fmaxf(sqrtf(sse), 1e-8f);
  const float sp = 1.0f / fmaxf(sqrtf(ssp), 1e-8f);
  const float sn = 1.0f / fmaxf(sqrtf(ssn), 1e-8f);

  int ue = __builtin_amdgcn_cvt_pk_fp8_f32(ev.x*se, ev.y*se, 0, false);
  ue     = __builtin_amdgcn_cvt_pk_fp8_f32(ev.z*se, ev.w*se, ue, true);
  int up = __builtin_amdgcn_cvt_pk_fp8_f32(pv.x*sp, pv.y*sp, 0, false);
  up     = __builtin_amdgcn_cvt_pk_fp8_f32(pv.z*sp, pv.w*sp, up, true);
  int un = __builtin_amdgcn_cvt_pk_fp8_f32(nv.x*sn, nv.y*sn, 0, false);
  un     = __builtin_amdgcn_cvt_pk_fp8_f32(nv.z*sn, nv.w*sn, un, true);
  eb[row * 64 + lane] = (uint32_t)ue;
  pb[row * 64 + lane] = (uint32_t)up;
  nb[row * 64 + lane] = (uint32_t)un;

  if (lane == 0) cbuf[row] = dep * se * sp * INV_T;
}

// Kernel 2: 128x128-tile fp8 GEMM (X @ Y^T) with FULL-K (256B) single-shot LDS staging.
// One vmcnt drain + one barrier per block; then 64 barrier-free MFMAs (32x32x16_fp8).
// Wave-tile 2x2 (64x64 per wave): LDS read traffic 128 KB/block.
// Swizzle: 16B-group gg of row r stored at slot gg ^ (r&7) -> 8 consecutive rows'
// b128 reads tile all 32 banks once; K-permutation identical for A and B.
__global__ __launch_bounds__(256, 2) void simexp_kernel(
    const uint8_t* __restrict__ eb, const uint8_t* __restrict__ pb,
    const uint8_t* __restrict__ nb, const float* __restrict__ cbuf,
    float* __restrict__ part) {
  __shared__ uint8_t As[BM * D];    // 32 KB
  __shared__ uint8_t Bs[BN * D];    // 32 KB
  __shared__ float cs[BM];          // 512 B -> 2 blocks/CU by LDS

  const int z = blockIdx.z;
  const uint8_t* __restrict__ A = z ? pb : eb;
  const uint8_t* __restrict__ B = z ? eb : nb;

  const int tid = threadIdx.x;
  const int wave = tid >> 6, lane = tid & 63;
  const int lane31 = lane & 31, half = lane >> 5;
  const int wr = wave & 1, wc = wave >> 1;
  const int rowTile = blockIdx.x * BM, colblk = blockIdx.y;
  const int colTile = colblk * BN;

  if (tid < BM) cs[tid] = cbuf[rowTile + tid];

  // Stage full 128x256B tiles: 2048 16B-chunks each, 8 per thread per operand.
#pragma unroll
  for (int t = 0; t < 8; ++t) {
    const int c = t * 256 + tid;
    const int r = c >> 4, sl = c & 15;
    const int gg = sl ^ (r & 7);                  // swizzled SOURCE group
    __builtin_amdgcn_global_load_lds(
        (gbl_u32*)(A + (size_t)(rowTile + r) * D + gg * 16),
        (lds_u32*)&As[c * 16], 16, 0, 0);
  }
#pragma unroll
  for (int t = 0; t < 8; ++t) {
    const int c = t * 256 + tid;
    const int r = c >> 4, sl = c & 15;
    const int gg = sl ^ (r & 7);
    __builtin_amdgcn_global_load_lds(
        (gbl_u32*)(B + (size_t)(colTile + r) * D + gg * 16),
        (lds_u32*)&Bs[c * 16], 16, 0, 0);
  }

  f32x16 acc[2][2];
#pragma unroll
  for (int mi = 0; mi < 2; ++mi)
#pragma unroll
    for (int ni = 0; ni < 2; ++ni)
#pragma unroll
      for (int r = 0; r < 16; ++r) acc[mi][ni][r] = 0.0f;

  __syncthreads();   // the ONLY barrier: drains staging, publishes As/Bs/cs

#pragma unroll
  for (int g = 0; g < 8; ++g) {
    const int gga = g * 2 + half;                 // this lane's logical 16B-group
    i64x2 af[2], bv[2];
#pragma unroll
    for (int mi = 0; mi < 2; ++mi) {
      const int rl = wr * 64 + mi * 32 + lane31;
      af[mi] = *(const i64x2*)&As[rl * D + ((gga ^ (rl & 7)) * 16)];
    }
#pragma unroll
    for (int ni = 0; ni < 2; ++ni) {
      const int cl = wc * 64 + ni * 32 + lane31;
      bv[ni] = *(const i64x2*)&Bs[cl * D + ((gga ^ (cl & 7)) * 16)];
    }
#pragma unroll
    for (int mi = 0; mi < 2; ++mi)
#pragma unroll
      for (int ni = 0; ni < 2; ++ni) {
        acc[mi][ni] =
            __builtin_amdgcn_mfma_f32_32x32x16_fp8_fp8(af[mi].x, bv[ni].x, acc[mi][ni], 0, 0, 0);
        acc[mi][ni] =
            __builtin_amdgcn_mfma_f32_32x32x16_fp8_fp8(af[mi].y, bv[ni].y, acc[mi][ni], 0, 0, 0);
      }
  }

  // Epilogue. 32x32 C/D: col=lane&31, row=(reg&3)+8*(reg>>2)+4*half (m74/m101).
  // Sum exp over this wave's 64 cols (2 ni in-lane + 32-lane shfl), write partials.
#pragma unroll
  for (int mi = 0; mi < 2; ++mi) {
#pragma unroll
    for (int reg = 0; reg < 16; ++reg) {
      const int rlocal = (reg & 3) + 8 * (reg >> 2) + 4 * half;
      const int rowl = wr * 64 + mi * 32 + rlocal;
      const float cv = cs[rowl];
      float v = __expf(acc[mi][0][reg] * INV_T - cv) +
                __expf(acc[mi][1][reg] * INV_T - cv);
      v += __shfl_xor(v, 1);
      v += __shfl_xor(v, 2);
      v += __shfl_xor(v, 4);
      v += __shfl_xor(v, 8);
      v += __shfl_xor(v, 16);
      if (lane31 == 0)
        part[((size_t)(z * 128 + colblk * 2 + wc)) * N + rowTile + rowl] = v;
    }
  }
}

// Kernel 3: per-row sum of 128 partials -> log/log1p -> block reduce -> atomicAdd(out).
__global__ __launch_bounds__(256) void reduce_kernel(const float* __restrict__ part,
                                                     float* __restrict__ out) {
  const int bid = blockIdx.x;              // 64 blocks
  const int z = bid >> 5;
  const int row = (bid & 31) * 256 + threadIdx.x;
  float s = 0.0f;
#pragma unroll 8
  for (int x = 0; x < 128; ++x)
    s += part[((size_t)(z * 128 + x)) * N + row];
  float val = z ? logf(s) : log1pf(s);
#pragma unroll
  for (int m = 1; m < 64; m <<= 1) val += __shfl_xor(val, m);
  __shared__ float sm[4];
  if ((threadIdx.x & 63) == 0) sm[threadIdx.x >> 6] = val;
  __syncthreads();
  if (threadIdx.x == 0)
    atomicAdd(out, (sm[0] + sm[1] + sm[2] + sm[3]) * (1.0f / (float)N));
}

extern "C" void kernel_launch(void* const* d_in, const int* in_sizes, int n_in,
                              void* d_out, int out_size, void* d_ws, size_t ws_size,
                              hipStream_t stream) {
  const float* e = (const float*)d_in[0];
  const float* p = (const float*)d_in[1];
  const float* n = (const float*)d_in[2];

  char* w = (char*)d_ws;
  uint8_t* eb = (uint8_t*)w;                                     // 2 MB
  uint8_t* pb = eb + (size_t)N * D;                              // 2 MB
  uint8_t* nb = pb + (size_t)N * D;                              // 2 MB
  float* cbuf = (float*)(nb + (size_t)N * D);                    // 32 KB
  float* part = cbuf + N;                                        // 2*128*8192*4 = 8 MB
  float* out = (float*)d_out;

  normalize_kernel<<<N / 4, 256, 0, stream>>>(e, p, n, (uint32_t*)eb, (uint32_t*)pb,
                                              (uint32_t*)nb, cbuf, out);
  simexp_kernel<<<dim3(N / BM, N / BN, 2), 256, 0, stream>>>(eb, pb, nb, cbuf, part);
  reduce_kernel<<<64, 256, 0, stream>>>(part, out);
}